// Round 7
// baseline (150.158 us; speedup 1.0000x reference)
//
#include <hip/hip_runtime.h>
#include <hip/hip_bf16.h>
#include <stdint.h>

#define T_DIM 2048
#define N_DIM 512
#define DV_DIM 128
#define NH 16          // B*H

typedef __bf16 bf16x8 __attribute__((ext_vector_type(8)));
typedef float f32x4 __attribute__((ext_vector_type(4)));
typedef float f32x2 __attribute__((ext_vector_type(2)));
typedef unsigned int u32x2 __attribute__((ext_vector_type(2)));
typedef unsigned int u32x4 __attribute__((ext_vector_type(4)));

__device__ __forceinline__ unsigned bf16rne(float x) {
  unsigned u = __builtin_bit_cast(unsigned, x);
  return (u + 0x7FFFu + ((u >> 16) & 1u)) >> 16;
}

__device__ __forceinline__ void load_lds16(const void* g, void* l) {
  __builtin_amdgcn_global_load_lds((const __attribute__((address_space(1))) void*)g,
                                   (__attribute__((address_space(3))) void*)l, 16, 0, 0);
}

// Q fragment load via raw asm: no compiler-tracked VMEM -> no implicit vmcnt
// drains inside the main loop (we control waits with counted vmcnt only).
#define QLOAD(dst, ptr, OFS) \
  asm volatile("global_load_dwordx4 %0, %1, off offset:" OFS \
               : "=v"(dst) : "v"(ptr))

// ---------------- RoPE: Q fp32 -> QR bf16  [bh][t][n] ----------------
__global__ void rope_kernel(const float* __restrict__ Q, const float* __restrict__ freqs,
                            unsigned int* __restrict__ qrOut) {
  const int total = NH * T_DIM * (N_DIM / 2);  // pairs
  for (int p = blockIdx.x * blockDim.x + threadIdx.x; p < total;
       p += gridDim.x * blockDim.x) {
    int n2 = p & 255;            // N/2 = 256
    int t = (p >> 8) & 2047;
    float f = freqs[2 * n2];
    f32x2 q = *(const f32x2*)(Q + 2 * (size_t)p);
    float ph = (float)t * f;
    ph = ph - floorf(ph);                 // revolutions in [0,1)
    float sn = __builtin_amdgcn_sinf(ph);
    float cn = __builtin_amdgcn_cosf(ph);
    float o0 = q.x * cn - q.y * sn;
    float o1 = q.y * cn + q.x * sn;
    qrOut[p] = bf16rne(o0) | (bf16rne(o1) << 16);
  }
}

// ---- V fp32 [bh][t][d] -> frag-linear bf16 blocks:
// vt32[bh][sblk32][slot j=df*64+lane][i=0..7] = V[s0+8*lg+i][16*df+lh]
__global__ void vtrans_kernel(const float* __restrict__ V, unsigned short* __restrict__ vt32) {
  __shared__ unsigned short tile[32][128];
  const int blk = blockIdx.x;
  const int bh = blk >> 6;
  const int sb = blk & 63;
  const float* src = V + ((size_t)bh * T_DIM + sb * 32) * DV_DIM;
  const int tid = threadIdx.x;
#pragma unroll
  for (int i = 0; i < 16; ++i) {
    int idx = i * 256 + tid;          // 0..4095 over [32][128]
    tile[idx >> 7][idx & 127] = (unsigned short)bf16rne(src[idx]);
  }
  __syncthreads();
  unsigned short* dst = vt32 + (size_t)blk * 4096;
#pragma unroll
  for (int jj = 0; jj < 2; ++jj) {
    int j = jj * 256 + tid;           // 0..511 slots of 8 shorts
    int df = j >> 6, ln = j & 63;
    int lh2 = ln & 15, lg2 = ln >> 4;
    unsigned short tmp[8];
#pragma unroll
    for (int i = 0; i < 8; ++i) tmp[i] = tile[8 * lg2 + i][16 * df + lh2];
    *(u32x4*)(dst + j * 8) = *(u32x4*)tmp;
  }
}

// ---------------- fused masked attention ----------------
// 1024 wgs x 128 thr (2 waves). Each XCD owns 2 heads outright (bid&7).
// wg = (head, pair p, kchunk c). Wave w covers 32 t-rows (2x 16-row tiles,
// k/v frags reused across tiles -> 0.56KB LDS read per MFMA). Diagonal
// pairing (blocks 31-p then p, seg1 reversed) = uniform 66 steps. K/V
// double-buffered frag-linear LDS; Q preloaded via asm for BOTH segments ->
// loop has no compiler-tracked VMEM; counted s_waitcnt vmcnt(8) only.
__global__ __launch_bounds__(128, 2)
void attn_kernel(const unsigned short* __restrict__ qr,
                 const unsigned short* __restrict__ vt32,
                 float* __restrict__ out) {
  __shared__ unsigned short k_lds[2][4096];  // [buf][frag f=st*4+ks][lane*8]
  __shared__ unsigned short v_lds[2][4096];  // [buf][frag df][lane*8]
  __shared__ unsigned short s_lds[4 * 512];  // [w*2+m][A-frag-linear 512]

  const int tid = threadIdx.x;
  const int w = tid >> 6;
  const int lane = tid & 63;
  const int lh = lane & 15;
  const int lg = lane >> 4;

  const int bid = blockIdx.x;
  const int u = bid >> 3;
  const int head = (bid & 7) + 8 * (u & 1);     // 2 heads per XCD
  const int c = u >> 5;                         // kchunk 0..3
  const int p = (((u >> 1) & 15) + 4 * c) & 15; // stagger flush steps per CU
  const int R0 = 31 - p, R1 = p;
  const int n0 = 2 * R0 + 2;                    // steps in segment 0; total 66

  const unsigned short* qr_h = qr + (size_t)head * (T_DIM * N_DIM);
  const unsigned short* vt_h = vt32 + (size_t)head * (64 * 4096);
  float* const out_h = out + (size_t)head * T_DIM * DV_DIM;

  // staging source offsets (bytes): 4 K-slots per thread, frag-linear dest
  int koff[4];
#pragma unroll
  for (int it = 0; it < 4; ++it) {
    int slot = it * 128 + tid;           // 0..511
    int f = slot >> 6, ln = slot & 63;
    int st = f >> 2, ks = f & 3;
    koff[it] = (st * 16 + (ln & 15)) * 1024 + c * 256 + ks * 64 + (ln >> 4) * 16;
  }

  // ---- Q for BOTH segments via asm loads (16x dwordx4 = 64 VGPR) ----
  u32x4 q0[2][4], q1[2][4];
  {
    const unsigned short* pa = qr_h + (size_t)(R0 * 64 + 32 * w + lh) * N_DIM + c * 128 + lg * 8;
    QLOAD(q0[0][0], pa, "0"); QLOAD(q0[0][1], pa, "64");
    QLOAD(q0[0][2], pa, "128"); QLOAD(q0[0][3], pa, "192");
    const unsigned short* pb = pa + 16 * N_DIM;
    QLOAD(q0[1][0], pb, "0"); QLOAD(q0[1][1], pb, "64");
    QLOAD(q0[1][2], pb, "128"); QLOAD(q0[1][3], pb, "192");
    const unsigned short* pc = qr_h + (size_t)(R1 * 64 + 32 * w + lh) * N_DIM + c * 128 + lg * 8;
    QLOAD(q1[0][0], pc, "0"); QLOAD(q1[0][1], pc, "64");
    QLOAD(q1[0][2], pc, "128"); QLOAD(q1[0][3], pc, "192");
    const unsigned short* pd = pc + 16 * N_DIM;
    QLOAD(q1[1][0], pd, "0"); QLOAD(q1[1][1], pd, "64");
    QLOAD(q1[1][2], pd, "128"); QLOAD(q1[1][3], pd, "192");
  }

  const f32x4 fzero = {0.f, 0.f, 0.f, 0.f};
  f32x4 o[2][8];
#pragma unroll
  for (int m = 0; m < 2; ++m)
#pragma unroll
    for (int d = 0; d < 8; ++d) o[m][d] = fzero;

  auto flushO = [&](int R) {
    const int tb2 = R * 64 + 32 * w;
#pragma unroll
    for (int m = 0; m < 2; ++m)
#pragma unroll
      for (int df = 0; df < 8; ++df)
#pragma unroll
        for (int r = 0; r < 4; ++r)
          atomicAdd(out_h + (size_t)(tb2 + 16 * m + 4 * lg + r) * DV_DIM + df * 16 + lh,
                    o[m][df][r]);
  };
  // 8 global_load_lds per thread per stage -> vmcnt unit = 8
  auto stage = [&](int sblk, int buf) {
    const char* kb = (const char*)qr_h + (size_t)sblk * 32768;
#pragma unroll
    for (int it = 0; it < 4; ++it)
      load_lds16(kb + koff[it], (char*)&k_lds[buf][0] + (it * 128 + tid) * 16);
    const char* vb = (const char*)vt_h + (size_t)sblk * 8192;
#pragma unroll
    for (int it = 0; it < 4; ++it)
      load_lds16(vb + (it * 128 + tid) * 16, (char*)&v_lds[buf][0] + (it * 128 + tid) * 16);
  };

  stage(0, 0);

  for (int t = 0; t < 66; ++t) {
    if (t == n0) {    // segment switch: emit block R0, swap in seg-1 Q
      flushO(R0);
#pragma unroll
      for (int m = 0; m < 2; ++m)
#pragma unroll
        for (int ks = 0; ks < 4; ++ks) q0[m][ks] = q1[m][ks];
#pragma unroll
      for (int m = 0; m < 2; ++m)
#pragma unroll
        for (int d = 0; d < 8; ++d) o[m][d] = fzero;
    }
    const int buf = t & 1;
    if (t + 1 < 66) {
      const int tn = t + 1;
      stage((tn < n0) ? tn : (65 - tn), buf ^ 1);
      asm volatile("s_waitcnt vmcnt(8)" ::: "memory");   // stage(t) landed
    } else {
      asm volatile("s_waitcnt vmcnt(0)" ::: "memory");
    }
    __builtin_amdgcn_s_barrier();
    __builtin_amdgcn_sched_barrier(0);

    const int sblk = (t < n0) ? t : (65 - t);
    const int s0 = sblk * 32;
    const int tbw = ((t < n0) ? R0 : R1) * 64 + 32 * w;
    const bool act0 = s0 < tbw + 16;        // tile m=0 (rows tbw..+15)
    const bool act1 = s0 < tbw + 32;        // tile m=1 (rows tbw+16..+31)

    if (act1) {
      // ---- QK^T swapped: S'[s][t] = K·Q^T; kf shared across both t-tiles ----
      f32x4 s1a = fzero, s1b = fzero, s0a = fzero, s0b = fzero;
#pragma unroll
      for (int ks = 0; ks < 4; ++ks) {
        bf16x8 kf0 = *(const bf16x8*)&k_lds[buf][ks * 512 + lane * 8];
        bf16x8 kf1 = *(const bf16x8*)&k_lds[buf][(4 + ks) * 512 + lane * 8];
        bf16x8 qm1 = __builtin_bit_cast(bf16x8, q0[1][ks]);
        s1a = __builtin_amdgcn_mfma_f32_16x16x32_bf16(kf0, qm1, s1a, 0, 0, 0);
        s1b = __builtin_amdgcn_mfma_f32_16x16x32_bf16(kf1, qm1, s1b, 0, 0, 0);
        if (act0) {
          bf16x8 qm0 = __builtin_bit_cast(bf16x8, q0[0][ks]);
          s0a = __builtin_amdgcn_mfma_f32_16x16x32_bf16(kf0, qm0, s0a, 0, 0, 0);
          s0b = __builtin_amdgcn_mfma_f32_16x16x32_bf16(kf1, qm0, s0b, 0, 0, 0);
        }
      }
      // ---- mask (keep s < t) + pack + b64 store, per tile ----
      auto maskStore = [&](f32x4 sa, f32x4 sb, int m) {
        const int tbm = tbw + 16 * m;
        if (s0 + 32 > tbm) {
          const int tcol = tbm + lh;
#pragma unroll
          for (int r = 0; r < 4; ++r) {
            if (s0 + 4 * lg + r >= tcol) sa[r] = 0.f;
            if (s0 + 16 + 4 * lg + r >= tcol) sb[r] = 0.f;
          }
        }
        u32x2 pk0, pk1;
        pk0[0] = bf16rne(sa[0]) | (bf16rne(sa[1]) << 16);
        pk0[1] = bf16rne(sa[2]) | (bf16rne(sa[3]) << 16);
        pk1[0] = bf16rne(sb[0]) | (bf16rne(sb[1]) << 16);
        pk1[1] = bf16rne(sb[2]) | (bf16rne(sb[3]) << 16);
        const int sb_ = (w * 2 + m) * 512 + lh * 8 + (lg >> 1) * 128 + (lg & 1) * 4;
        *(u32x2*)&s_lds[sb_] = pk0;
        *(u32x2*)&s_lds[sb_ + 256] = pk1;
      };
      maskStore(s1a, s1b, 1);
      if (act0) maskStore(s0a, s0b, 0);

      // ---- PV: O += P·V ; vf shared across both t-tiles ----
      bf16x8 pa1 = *(const bf16x8*)&s_lds[(w * 2 + 1) * 512 + lane * 8];
      bf16x8 pa0 = pa1;
      if (act0) pa0 = *(const bf16x8*)&s_lds[(w * 2) * 512 + lane * 8];
#pragma unroll
      for (int df = 0; df < 8; ++df) {
        bf16x8 vf = *(const bf16x8*)&v_lds[buf][df * 512 + lane * 8];
        o[1][df] = __builtin_amdgcn_mfma_f32_16x16x32_bf16(pa1, vf, o[1][df], 0, 0, 0);
        if (act0)
          o[0][df] = __builtin_amdgcn_mfma_f32_16x16x32_bf16(pa0, vf, o[0][df], 0, 0, 0);
      }
    }
    asm volatile("s_waitcnt lgkmcnt(0)" ::: "memory");
    __builtin_amdgcn_sched_barrier(0);
    __builtin_amdgcn_s_barrier();   // buf free for overwrite next step
  }

  flushO(R1);
}

extern "C" void kernel_launch(void* const* d_in, const int* in_sizes, int n_in,
                              void* d_out, int out_size, void* d_ws, size_t ws_size,
                              hipStream_t stream) {
  const float* Q = (const float*)d_in[0];
  const float* V = (const float*)d_in[1];
  const float* freqs = (const float*)d_in[2];
  float* out = (float*)d_out;

  unsigned short* qr = (unsigned short*)d_ws;                        // 32 MB
  unsigned short* vt = qr + (size_t)NH * T_DIM * N_DIM;              // 8 MB

  hipMemsetAsync(out, 0, (size_t)NH * T_DIM * DV_DIM * sizeof(float), stream);
  hipLaunchKernelGGL(rope_kernel, dim3(2048), dim3(256), 0, stream,
                     Q, freqs, (unsigned int*)qr);
  hipLaunchKernelGGL(vtrans_kernel, dim3(NH * 64), dim3(256), 0, stream, V, vt);
  hipLaunchKernelGGL(attn_kernel, dim3(1024), dim3(128), 0, stream, qr, vt, out);
}

// Round 10
// 140.353 us; speedup vs baseline: 1.0699x; 1.0699x over previous
//
#include <hip/hip_runtime.h>
#include <hip/hip_bf16.h>
#include <stdint.h>

#define T_DIM 2048
#define N_DIM 512
#define DV_DIM 128
#define NH 16          // B*H

typedef __bf16 bf16x8 __attribute__((ext_vector_type(8)));
typedef float f32x4 __attribute__((ext_vector_type(4)));
typedef float f32x2 __attribute__((ext_vector_type(2)));
typedef unsigned int u32x2 __attribute__((ext_vector_type(2)));
typedef unsigned int u32x4 __attribute__((ext_vector_type(4)));

__device__ __forceinline__ unsigned bf16rne(float x) {
  unsigned u = __builtin_bit_cast(unsigned, x);
  return (u + 0x7FFFu + ((u >> 16) & 1u)) >> 16;
}

__device__ __forceinline__ void load_lds16(const void* g, void* l) {
  __builtin_amdgcn_global_load_lds((const __attribute__((address_space(1))) void*)g,
                                   (__attribute__((address_space(3))) void*)l, 16, 0, 0);
}

#define QLOAD(dst, ptr, OFS) \
  asm volatile("global_load_dwordx4 %0, %1, off offset:" OFS \
               : "=v"(dst) : "v"(ptr))

// ---------------- RoPE: Q fp32 -> QR bf16  [bh][t][n] ----------------
__global__ void rope_kernel(const float* __restrict__ Q, const float* __restrict__ freqs,
                            unsigned int* __restrict__ qrOut) {
  const int total = NH * T_DIM * (N_DIM / 2);  // pairs
  for (int p = blockIdx.x * blockDim.x + threadIdx.x; p < total;
       p += gridDim.x * blockDim.x) {
    int n2 = p & 255;            // N/2 = 256
    int t = (p >> 8) & 2047;
    float f = freqs[2 * n2];
    f32x2 q = *(const f32x2*)(Q + 2 * (size_t)p);
    float ph = (float)t * f;
    ph = ph - floorf(ph);                 // revolutions in [0,1)
    float sn = __builtin_amdgcn_sinf(ph);
    float cn = __builtin_amdgcn_cosf(ph);
    float o0 = q.x * cn - q.y * sn;
    float o1 = q.y * cn + q.x * sn;
    qrOut[p] = bf16rne(o0) | (bf16rne(o1) << 16);
  }
}

// ---- V fp32 [bh][t][d] -> frag-linear bf16 blocks (16x16x32 B-frag):
// vt32[bh][sblk32][slot j=df*64+lane][i=0..7] = V[s0+8*lg+i][16*df+lh]
__global__ void vtrans_kernel(const float* __restrict__ V, unsigned short* __restrict__ vt32) {
  __shared__ unsigned short tile[32][128];
  const int blk = blockIdx.x;
  const int bh = blk >> 6;
  const int sb = blk & 63;
  const float* src = V + ((size_t)bh * T_DIM + sb * 32) * DV_DIM;
  const int tid = threadIdx.x;
#pragma unroll
  for (int i = 0; i < 16; ++i) {
    int idx = i * 256 + tid;          // 0..4095 over [32][128]
    tile[idx >> 7][idx & 127] = (unsigned short)bf16rne(src[idx]);
  }
  __syncthreads();
  unsigned short* dst = vt32 + (size_t)blk * 4096;
#pragma unroll
  for (int jj = 0; jj < 2; ++jj) {
    int j = jj * 256 + tid;           // slot 0..511
    int df = j >> 6, ln = j & 63;
    int lh2 = ln & 15, lg2 = ln >> 4;
    unsigned short tmp[8];
#pragma unroll
    for (int i = 0; i < 8; ++i) tmp[i] = tile[8 * lg2 + i][16 * df + lh2];
    *(u32x4*)(dst + j * 8) = *(u32x4*)tmp;
  }
}

// ---------------- fused masked attention ----------------
// 512 wgs x 256 thr (4 waves, 2 wgs/CU -> 8 waves/CU). wg = (head pinned to
// XCD, block-pair ph 0..7, kchunk c). Wave w owns 32 t-rows (2x 16-row
// tiles); wg covers 128 rows -> staged K/V block amortized over 2x the MFMA
// of v7 (LDS-port bound). Diagonal pairing over 128-row blocks: seg0 =
// block 15-ph (64-4ph steps), seg1 = block ph reversed (sblk = 67-t) ->
// uniform 68 steps, cohort-aligned s-blocks. K/V double-buffered frag-linear
// LDS (reads lane*16B, conflict-free); counted s_waitcnt vmcnt(4); Q for
// both segments preloaded via asm + vmcnt(0) (spill-proof); fp32 atomicAdd.
__global__ __launch_bounds__(256, 2)
void attn_kernel(const unsigned short* __restrict__ qr,
                 const unsigned short* __restrict__ vt32,
                 float* __restrict__ out) {
  __shared__ unsigned short k_lds[2][4096];  // [buf][frag f=st*4+ks][lane*8]
  __shared__ unsigned short v_lds[2][4096];  // [buf][frag df][lane*8]
  __shared__ unsigned short s_lds[8 * 512];  // [w*2+m][A-frag-linear 512]

  const int tid = threadIdx.x;
  const int w = tid >> 6;
  const int lane = tid & 63;
  const int lh = lane & 15;
  const int lg = lane >> 4;

  const int bid = blockIdx.x;
  const int u = bid >> 3;
  const int head = (bid & 7) + 8 * (u & 1);   // 2 heads per XCD
  const int v2 = u >> 1;                      // 0..31
  const int c = v2 & 3;                       // kchunk
  const int ph = ((v2 >> 2) + 2 * c) & 7;     // pair, staggered per kchunk
  const int b0 = 15 - ph, b1 = ph;            // 128-row blocks
  const int n0 = 64 - 4 * ph;                 // seg0 steps; total 68

  const unsigned short* qr_h = qr + (size_t)head * (T_DIM * N_DIM);
  const unsigned short* vt_h = vt32 + (size_t)head * (64 * 4096);
  float* const out_h = out + (size_t)head * T_DIM * DV_DIM;

  // staging source offsets (bytes): 2 K slots/thread, frag-linear dest
  int koff[2];
#pragma unroll
  for (int it = 0; it < 2; ++it) {
    int slot = it * 256 + tid;           // 0..511
    int f = slot >> 6, l = slot & 63;
    int st = f >> 2, ks = f & 3;
    koff[it] = (st * 16 + (l & 15)) * 1024 + c * 256 + ks * 64 + (l >> 4) * 16;
  }

  // ---- Q for BOTH segments via asm loads + vmcnt(0) (16x dwordx4) ----
  u32x4 q0[2][4], q1[2][4];
  {
    const unsigned short* pa = qr_h + (size_t)(b0 * 128 + 32 * w + lh) * N_DIM + c * 128 + lg * 8;
    QLOAD(q0[0][0], pa, "0");   QLOAD(q0[0][1], pa, "64");
    QLOAD(q0[0][2], pa, "128"); QLOAD(q0[0][3], pa, "192");
    const unsigned short* pb = pa + 16 * N_DIM;
    QLOAD(q0[1][0], pb, "0");   QLOAD(q0[1][1], pb, "64");
    QLOAD(q0[1][2], pb, "128"); QLOAD(q0[1][3], pb, "192");
    const unsigned short* pc = qr_h + (size_t)(b1 * 128 + 32 * w + lh) * N_DIM + c * 128 + lg * 8;
    QLOAD(q1[0][0], pc, "0");   QLOAD(q1[0][1], pc, "64");
    QLOAD(q1[0][2], pc, "128"); QLOAD(q1[0][3], pc, "192");
    const unsigned short* pd = pc + 16 * N_DIM;
    QLOAD(q1[1][0], pd, "0");   QLOAD(q1[1][1], pd, "64");
    QLOAD(q1[1][2], pd, "128"); QLOAD(q1[1][3], pd, "192");
  }

  const f32x4 fzero = {0.f, 0.f, 0.f, 0.f};
  f32x4 o[2][8];
#pragma unroll
  for (int m = 0; m < 2; ++m)
#pragma unroll
    for (int d = 0; d < 8; ++d) o[m][d] = fzero;

  auto flushO = [&](int b) {
    const int tb2 = b * 128 + 32 * w;
#pragma unroll
    for (int m = 0; m < 2; ++m)
#pragma unroll
      for (int df = 0; df < 8; ++df)
#pragma unroll
        for (int r = 0; r < 4; ++r)
          atomicAdd(out_h + (size_t)(tb2 + 16 * m + 4 * lg + r) * DV_DIM + df * 16 + lh,
                    o[m][df][r]);
  };
  // 4 global_load_lds per thread per stage -> vmcnt unit = 4
  auto stage = [&](int sblk, int buf) {
    const char* kb = (const char*)qr_h + (size_t)sblk * 32768;
#pragma unroll
    for (int it = 0; it < 2; ++it)
      load_lds16(kb + koff[it], (char*)&k_lds[buf][0] + (it * 256 + tid) * 16);
    const char* vb = (const char*)vt_h + (size_t)sblk * 8192;
#pragma unroll
    for (int it = 0; it < 2; ++it)
      load_lds16(vb + (it * 256 + tid) * 16, (char*)&v_lds[buf][0] + (it * 256 + tid) * 16);
  };

  stage(0, 0);
  asm volatile("s_waitcnt vmcnt(0)" ::: "memory");  // qf (and stage0) valid

  for (int t = 0; t < 68; ++t) {
    if (t == n0) {    // segment seam: emit block b0, swap in seg-1 Q
      flushO(b0);
#pragma unroll
      for (int m = 0; m < 2; ++m)
#pragma unroll
        for (int ks = 0; ks < 4; ++ks) q0[m][ks] = q1[m][ks];
#pragma unroll
      for (int m = 0; m < 2; ++m)
#pragma unroll
        for (int d = 0; d < 8; ++d) o[m][d] = fzero;
    }
    const int buf = t & 1;
    if (t + 1 < 68) {
      const int tn = t + 1;
      stage((tn < n0) ? tn : (67 - tn), buf ^ 1);
      asm volatile("s_waitcnt vmcnt(4)" ::: "memory");   // stage(t) landed
    } else {
      asm volatile("s_waitcnt vmcnt(0)" ::: "memory");
    }
    __builtin_amdgcn_s_barrier();
    __builtin_amdgcn_sched_barrier(0);

    const int sblk = (t < n0) ? t : (67 - t);
    const int s0 = sblk * 32;
    const int tbw = ((t < n0) ? b0 : b1) * 128 + 32 * w;
    const bool act0 = s0 < tbw + 16;        // tile m=0 (rows tbw..+15)
    const bool act1 = s0 < tbw + 32;        // tile m=1 (rows tbw+16..+31)

    if (act1) {
      // ---- QK^T swapped: S'[s][t] = K·Q^T; kf shared across both t-tiles ----
      f32x4 s1a = fzero, s1b = fzero, s0a = fzero, s0b = fzero;
#pragma unroll
      for (int ks = 0; ks < 4; ++ks) {
        bf16x8 kf0 = *(const bf16x8*)&k_lds[buf][ks * 512 + lane * 8];
        bf16x8 kf1 = *(const bf16x8*)&k_lds[buf][(4 + ks) * 512 + lane * 8];
        bf16x8 qm1 = __builtin_bit_cast(bf16x8, q0[1][ks]);
        s1a = __builtin_amdgcn_mfma_f32_16x16x32_bf16(kf0, qm1, s1a, 0, 0, 0);
        s1b = __builtin_amdgcn_mfma_f32_16x16x32_bf16(kf1, qm1, s1b, 0, 0, 0);
        if (act0) {
          bf16x8 qm0 = __builtin_bit_cast(bf16x8, q0[0][ks]);
          s0a = __builtin_amdgcn_mfma_f32_16x16x32_bf16(kf0, qm0, s0a, 0, 0, 0);
          s0b = __builtin_amdgcn_mfma_f32_16x16x32_bf16(kf1, qm0, s0b, 0, 0, 0);
        }
      }
      // ---- mask (keep s < t) + pack + b64 store, per tile ----
      auto maskStore = [&](f32x4 sa, f32x4 sb, int m) {
        const int tbm = tbw + 16 * m;
        if (s0 + 32 > tbm) {
          const int tcol = tbm + lh;
#pragma unroll
          for (int r = 0; r < 4; ++r) {
            if (s0 + 4 * lg + r >= tcol) sa[r] = 0.f;
            if (s0 + 16 + 4 * lg + r >= tcol) sb[r] = 0.f;
          }
        }
        u32x2 pk0, pk1;
        pk0[0] = bf16rne(sa[0]) | (bf16rne(sa[1]) << 16);
        pk0[1] = bf16rne(sa[2]) | (bf16rne(sa[3]) << 16);
        pk1[0] = bf16rne(sb[0]) | (bf16rne(sb[1]) << 16);
        pk1[1] = bf16rne(sb[2]) | (bf16rne(sb[3]) << 16);
        const int sb_ = (w * 2 + m) * 512 + lh * 8 + (lg >> 1) * 128 + (lg & 1) * 4;
        *(u32x2*)&s_lds[sb_] = pk0;
        *(u32x2*)&s_lds[sb_ + 256] = pk1;
      };
      maskStore(s1a, s1b, 1);
      if (act0) maskStore(s0a, s0b, 0);

      // ---- PV: O += P·V ; vf shared across both t-tiles ----
      bf16x8 pa1 = *(const bf16x8*)&s_lds[(w * 2 + 1) * 512 + lane * 8];
      bf16x8 pa0 = pa1;
      if (act0) pa0 = *(const bf16x8*)&s_lds[(w * 2) * 512 + lane * 8];
#pragma unroll
      for (int df = 0; df < 8; ++df) {
        bf16x8 vf = *(const bf16x8*)&v_lds[buf][df * 512 + lane * 8];
        o[1][df] = __builtin_amdgcn_mfma_f32_16x16x32_bf16(pa1, vf, o[1][df], 0, 0, 0);
        if (act0)
          o[0][df] = __builtin_amdgcn_mfma_f32_16x16x32_bf16(pa0, vf, o[0][df], 0, 0, 0);
      }
    }
    asm volatile("s_waitcnt lgkmcnt(0)" ::: "memory");
    __builtin_amdgcn_sched_barrier(0);
    __builtin_amdgcn_s_barrier();   // buf free for overwrite next step
  }

  flushO(b1);
}

extern "C" void kernel_launch(void* const* d_in, const int* in_sizes, int n_in,
                              void* d_out, int out_size, void* d_ws, size_t ws_size,
                              hipStream_t stream) {
  const float* Q = (const float*)d_in[0];
  const float* V = (const float*)d_in[1];
  const float* freqs = (const float*)d_in[2];
  float* out = (float*)d_out;

  unsigned short* qr = (unsigned short*)d_ws;                        // 32 MB
  unsigned short* vt = qr + (size_t)NH * T_DIM * N_DIM;              // 8 MB

  hipMemsetAsync(out, 0, (size_t)NH * T_DIM * DV_DIM * sizeof(float), stream);
  hipLaunchKernelGGL(rope_kernel, dim3(2048), dim3(256), 0, stream,
                     Q, freqs, (unsigned int*)qr);
  hipLaunchKernelGGL(vtrans_kernel, dim3(NH * 64), dim3(256), 0, stream, V, vt);
  hipLaunchKernelGGL(attn_kernel, dim3(512), dim3(256), 0, stream, qr, vt, out);
}